// Round 6
// baseline (522.236 us; speedup 1.0000x reference)
//
#include <hip/hip_runtime.h>
#include <hip/hip_bf16.h>

#define B_N 16
#define LQ_N 2048
#define LK_N 2048
#define D_N 64

typedef __attribute__((ext_vector_type(8))) __bf16 bf16x8;
typedef __attribute__((ext_vector_type(4))) float f32x4;
typedef __attribute__((ext_vector_type(2))) unsigned u32x2;
typedef __attribute__((ext_vector_type(4))) unsigned u32x4;

__device__ __forceinline__ unsigned cvt_pk_bf16(float lo, float hi) {
  unsigned r;
  asm("v_cvt_pk_bf16_f32 %0, %1, %2" : "=v"(r) : "v"(lo), "v"(hi));
  return r;
}

__device__ __forceinline__ void gl_lds16(const float* g, float* l) {
  __builtin_amdgcn_global_load_lds(
      (const __attribute__((address_space(1))) void*)g,
      (__attribute__((address_space(3))) void*)l, 16, 0, 0);
}

#define WAIT_VMC(N)  do { asm volatile("s_waitcnt vmcnt(" #N ")" ::: "memory"); __builtin_amdgcn_sched_barrier(0); } while (0)
#define WAIT_LGKM0() do { asm volatile("s_waitcnt lgkmcnt(0)" ::: "memory");    __builtin_amdgcn_sched_barrier(0); } while (0)
#define SBAR()       __builtin_amdgcn_sched_barrier(0)

// ---------- pass 1: global sum & max of time_diff ----------
__global__ __launch_bounds__(256) void red1_kernel(const float* __restrict__ td,
                                                   float* __restrict__ ws) {
  const int tid = threadIdx.x;
  const int gid = blockIdx.x * 256 + tid;
  float s = 0.f, mx = -1e30f;
  const float4* p = reinterpret_cast<const float4*>(td);
  for (int i = gid; i < 16777216; i += 524288) {
    float4 x = p[i];
    s += (x.x + x.y) + (x.z + x.w);
    mx = fmaxf(mx, fmaxf(fmaxf(x.x, x.y), fmaxf(x.z, x.w)));
  }
#pragma unroll
  for (int m = 1; m < 64; m <<= 1) {
    s += __shfl_xor(s, m, 64);
    mx = fmaxf(mx, __shfl_xor(mx, m, 64));
  }
  __shared__ float ss[4], sm[4];
  if ((tid & 63) == 0) { ss[tid >> 6] = s; sm[tid >> 6] = mx; }
  __syncthreads();
  if (tid == 0) {
    ws[blockIdx.x]        = (ss[0] + ss[1]) + (ss[2] + ss[3]);
    ws[2048 + blockIdx.x] = fmaxf(fmaxf(sm[0], sm[1]), fmaxf(sm[2], sm[3]));
  }
}

// final reduce + scalar prep + mask-layout detection (byte vs int32 bool)
__global__ __launch_bounds__(256) void red2_kernel(const float* __restrict__ tpw,
                                                   const unsigned* __restrict__ mku,
                                                   float* __restrict__ ws) {
  const int tid = threadIdx.x;
  double s = 0.0; float mx = -1e30f;
  for (int i = tid; i < 2048; i += 256) { s += (double)ws[i]; mx = fmaxf(mx, ws[2048 + i]); }
#pragma unroll
  for (int m = 1; m < 64; m <<= 1) {
    s += __shfl_xor(s, m, 64);
    mx = fmaxf(mx, __shfl_xor(mx, m, 64));
  }
  unsigned big = 0;
  for (int i = tid; i < 1024; i += 256) big |= (mku[i] > 1u) ? 1u : 0u;
  const int anyw = __any(big != 0);
  __shared__ double sd[4]; __shared__ float sm[4]; __shared__ int sa[4];
  if ((tid & 63) == 0) { sd[tid >> 6] = s; sm[tid >> 6] = mx; sa[tid >> 6] = anyw; }
  __syncthreads();
  if (tid == 0) {
    double tot = (sd[0] + sd[1]) + (sd[2] + sd[3]);
    float m4 = fmaxf(fmaxf(sm[0], sm[1]), fmaxf(sm[2], sm[3]));
    double mean = tot / 67108864.0;
    float inv_mean = (float)(1.0 / mean);
    float sp = log1pf(__expf(tpw[0]));
    ws[4096] = inv_mean;
    ws[4097] = sp * m4 * inv_mean;                      // bias_c
    ws[4098] = (sa[0] | sa[1] | sa[2] | sa[3]) ? 1.f : 0.f;  // 1 = byte mask, 0 = int32
    ws[4099] = 2.718281828459045f + sp * m4 * inv_mean; // ec = e + bias_c
  }
}

// ---------- pass 2: fused QK^T + bias + mask + softmax + attn-write + PV ----------
// 512 thr (8 waves), 16 q-rows/block. SWAPPED QK^T (mfma(K,Q) -> S^T tile): each lane
// holds q-row=lrow, 4 consecutive j -> td/mask/attn become float4/u32/dwordx4 per chunk.
// Wave-private K/V chunks, global_load_lds double-buffered depth-2; td/mask 3-deep
// register prefetch; exp2-domain softmax; counted vmcnt (never 0 mid-loop).
__global__ __launch_bounds__(512, 4) void attn_kernel(
    const float* __restrict__ q, const float* __restrict__ kp, const float* __restrict__ vp,
    const float* __restrict__ td, const unsigned char* __restrict__ maskb,
    const float* __restrict__ tmwp, const float* __restrict__ ws,
    float* __restrict__ out, float* __restrict__ attn) {

  __shared__ float regA[8][2][1024];         // 64 KB: per-wave double-buffered K/V chunk
  __shared__ float Qs[16 * 68];
  __shared__ unsigned short Ps[8][16 * 40];  // per-wave P bridge, stride 40 (16B-aligned rows)
  __shared__ float rsum[8][16];

  const int tid  = threadIdx.x;
  const int w    = tid >> 6;
  const int lane = tid & 63;
  const int lrow = lane & 15;
  const int lgrp = lane >> 4;

  const int b     = blockIdx.x >> 7;
  const int qbase = (blockIdx.x & 127) << 4;

  const float inv_mean = ws[4096];
  const float ec       = ws[4099];                       // e + bias_c
  const float tmw      = tmwp[0];
  const float sc       = tmw * 2.0813689810056077f;      // tmw * log2e / ln2
  const int   msh      = (ws[4098] != 0.f) ? 0 : 2;

  // ---- stage Q f32, pre-scaled by log2e/temperature ----
  {
    const float qscale = 0.18033688011112042f;           // 0.125 * log2e
    const int g = tid * 2, row = g >> 6, col = g & 63;
    const float* qp0 = q + ((size_t)(b * LQ_N + qbase + row) << 6) + col;
    Qs[row * 68 + col]     = qp0[0] * qscale;
    Qs[row * 68 + col + 1] = qp0[1] * qscale;
  }
  __syncthreads();

  bf16x8 qa[2];
#pragma unroll
  for (int h = 0; h < 2; ++h) {
    f32x4 a0 = *(const f32x4*)&Qs[lrow * 68 + h * 32 + lgrp * 8];
    f32x4 a1 = *(const f32x4*)&Qs[lrow * 68 + h * 32 + lgrp * 8 + 4];
    u32x4 kd = { cvt_pk_bf16(a0[0], a0[1]), cvt_pk_bf16(a0[2], a0[3]),
                 cvt_pk_bf16(a1[0], a1[1]), cvt_pk_bf16(a1[2], a1[3]) };
    qa[h] = __builtin_bit_cast(bf16x8, kd);
  }

  // 32-bit element offsets. Elementwise layout (post-swap): q-row = lrow, j-base = lgrp*4.
  const unsigned qrow = (unsigned)(b * LQ_N + qbase + lrow);
  const unsigned tdo0 = (qrow << 11) + (unsigned)(w * 16 + lgrp * 4);
  const unsigned kvo0 = ((unsigned)b << 17) + ((unsigned)w << 10);
  const unsigned pA = (lgrp << 6) + ((lrow ^ lgrp)       << 2);
  const unsigned pB = (lgrp << 6) + ((lrow ^ (lgrp + 4)) << 2);

  // wave-private DMA: 16 rows x 64 f32; LDS dest linear, source slot-permuted
  auto dma16 = [&](const float* src_base, int c, int pb) {
    const unsigned base = kvo0 + (unsigned)c * 8192u;
    gl_lds16(src_base + (base         + pA), &regA[w][pb][0]);
    gl_lds16(src_base + (base +  256u + pB), &regA[w][pb][256]);
    gl_lds16(src_base + (base +  512u + pA), &regA[w][pb][512]);
    gl_lds16(src_base + (base +  768u + pB), &regA[w][pb][768]);
  };

  // td float4 (NT) + mask 4-wide, one load each
  auto ldtd = [&](int c, f32x4* tdv, unsigned* mk4) {
    const unsigned to = tdo0 + (unsigned)c * 128u;
    *tdv = __builtin_nontemporal_load(reinterpret_cast<const f32x4*>(td + to));
    if (msh == 0) {
      *mk4 = *reinterpret_cast<const unsigned*>(maskb + to);
    } else {
      u32x4 m = __builtin_nontemporal_load(
          reinterpret_cast<const u32x4*>(maskb + ((size_t)to << 2)));
      *mk4 = (m[0] & 1u) | ((m[1] & 1u) << 8) | ((m[2] & 1u) << 16) | ((m[3] & 1u) << 24);
    }
  };

  // ---- phase 1: QK^T(swapped) + bias + mask + exp2 ----
  dma16(kp, 0, 0); SBAR();
  dma16(kp, 1, 1); SBAR();
  f32x4    tdb[3];
  unsigned mkb[3];
  ldtd(0, &tdb[0], &mkb[0]); SBAR();
  ldtd(1, &tdb[1], &mkb[1]); SBAR();

  float rs = 0.f;
  u32x2 E[16];

#pragma unroll
  for (int c = 0; c < 16; ++c) {
    // top: ensure dma(c) done. seq: D0 D1 L0 L1 | it c: L(c+2), D(c+2)
    if (c == 0)       { WAIT_VMC(8);  }
    else if (c == 1)  { WAIT_VMC(10); }
    else if (c == 15) { WAIT_VMC(0);  }
    else              { WAIT_VMC(6);  }

    if (c < 14) { ldtd(c + 2, &tdb[(c + 2) % 3], &mkb[(c + 2) % 3]); SBAR(); }

    f32x4 acc = {0.f, 0.f, 0.f, 0.f};
#pragma unroll
    for (int h = 0; h < 2; ++h) {
      const int g0 = (h * 8 + lgrp * 2 + 0) ^ (lrow & 7);
      const int g1 = (h * 8 + lgrp * 2 + 1) ^ (lrow & 7);
      f32x4 ka = *(const f32x4*)&regA[w][c & 1][lrow * 64 + g0 * 4];
      f32x4 kc = *(const f32x4*)&regA[w][c & 1][lrow * 64 + g1 * 4];
      u32x4 kd = { cvt_pk_bf16(ka[0], ka[1]), cvt_pk_bf16(ka[2], ka[3]),
                   cvt_pk_bf16(kc[0], kc[1]), cvt_pk_bf16(kc[2], kc[3]) };
      // SWAPPED: A=K, B=Q -> D[j][q]; lane holds q=lrow, j = base + lgrp*4 + i
      acc = __builtin_amdgcn_mfma_f32_16x16x32_bf16(__builtin_bit_cast(bf16x8, kd), qa[h],
                                                    acc, 0, 0, 0);
    }
    WAIT_LGKM0();                              // buffer (c&1) reusable
    if (c < 14) { dma16(kp, c + 2, c & 1); SBAR(); }

    // mid: ensure ldtd(c) done
    if (c == 0)       { WAIT_VMC(8);  }
    else if (c == 1)  { WAIT_VMC(12); }
    else if (c == 14) { WAIT_VMC(10); }
    else if (c == 15) { WAIT_VMC(0);  }
    else              { WAIT_VMC(16); }

    const f32x4    tv  = tdb[c % 3];
    const unsigned mk4 = mkb[c % 3];
    float e4[4];
#pragma unroll
    for (int i = 0; i < 4; ++i) {
      const float z  = __builtin_fmaf(tv[i], inv_mean, ec);
      const float l2 = __builtin_amdgcn_logf(z);          // log2(z)
      const float r  = __builtin_amdgcn_rcpf(l2);
      const float sv = __builtin_fmaf(sc, r, acc[i]);
      const float e  = ((mk4 >> (8 * i)) & 0xffu) ? 0.f : __builtin_amdgcn_exp2f(sv);
      e4[i] = e;
      rs += e;
    }
    E[c] = u32x2{ cvt_pk_bf16(e4[0], e4[1]), cvt_pk_bf16(e4[2], e4[3]) };
  }

  // ---- V DMA prologue: latency hides under the rsum reduction ----
  dma16(vp, 0, 0); SBAR();
  dma16(vp, 1, 1); SBAR();

  // ---- row sum (q-row = lrow): reduce over lgrp, then cross-wave ----
  rs += __shfl_xor(rs, 16, 64);
  rs += __shfl_xor(rs, 32, 64);
  if (lgrp == 0) rsum[w][lrow] = rs;
  __syncthreads();
  float invl;
  {
    float s = 0.f;
#pragma unroll
    for (int w2 = 0; w2 < 8; ++w2) s += rsum[w2][lrow];
    invl = __fdividef(1.f, s);
  }

  // ---- phase 2: attn write + PV ----
  f32x4 oacc[4];
#pragma unroll
  for (int n = 0; n < 4; ++n) oacc[n] = {0.f, 0.f, 0.f, 0.f};

  const u32x4 zz = {0u, 0u, 0u, 0u};
#pragma unroll
  for (int c = 0; c < 16; ++c) {
    // top: ensure dma(c) done. seq: D0 D1 | it c: D(c+2), S(c)  (S = 1 store)
    if (c == 0)       { WAIT_VMC(4); }
    else if (c == 1)  { WAIT_VMC(5); }
    else if (c == 15) { WAIT_VMC(2); }
    else              { WAIT_VMC(6); }

    const unsigned ex = E[c][0], ey = E[c][1];
    f32x4 pv;
    pv[0] = __uint_as_float(ex << 16)         * invl;
    pv[1] = __uint_as_float(ex & 0xffff0000u) * invl;
    pv[2] = __uint_as_float(ey << 16)         * invl;
    pv[3] = __uint_as_float(ey & 0xffff0000u) * invl;

    // P bridge: row = lrow (q), cols lgrp*4..+3 -> one b64 write
    const unsigned d01 = cvt_pk_bf16(pv[0], pv[1]);
    const unsigned d23 = cvt_pk_bf16(pv[2], pv[3]);
    *reinterpret_cast<u32x2*>(&Ps[w][lrow * 40 + lgrp * 4]) = u32x2{ d01, d23 };

    bf16x8 pa;
    if (lgrp < 2) pa = *(const bf16x8*)&Ps[w][lrow * 40 + lgrp * 8];
    else          pa = __builtin_bit_cast(bf16x8, zz);

#pragma unroll
    for (int n = 0; n < 4; ++n) {
      u32x4 vd;
      if (lgrp < 2) {
        float vv[8];
#pragma unroll
        for (int e = 0; e < 8; ++e) {
          const int r    = lgrp * 8 + e;
          const int dcol = n * 16 + lrow;
          const int slot = (dcol >> 2) ^ (r & 7);
          vv[e] = regA[w][c & 1][r * 64 + slot * 4 + (dcol & 3)];
        }
        vd = u32x4{ cvt_pk_bf16(vv[0], vv[1]), cvt_pk_bf16(vv[2], vv[3]),
                    cvt_pk_bf16(vv[4], vv[5]), cvt_pk_bf16(vv[6], vv[7]) };
      } else {
        vd = zz;
      }
      oacc[n] = __builtin_amdgcn_mfma_f32_16x16x32_bf16(pa, __builtin_bit_cast(bf16x8, vd),
                                                        oacc[n], 0, 0, 0);
    }

    WAIT_LGKM0();                              // all regA[c&1] reads done
    if (c < 14) { dma16(vp, c + 2, c & 1); SBAR(); }

    __builtin_nontemporal_store(pv, reinterpret_cast<f32x4*>(attn + tdo0 + (unsigned)c * 128u));
  }

  // ---- cross-wave O reduction ----
#pragma unroll
  for (int n = 0; n < 4; ++n)
#pragma unroll
    for (int i = 0; i < 4; ++i)
      regA[w][0][(lgrp * 4 + i) * 64 + n * 16 + lrow] = oacc[n][i];
  __syncthreads();
  for (int i2 = tid; i2 < 1024; i2 += 512) {
    float s = 0.f;
#pragma unroll
    for (int w2 = 0; w2 < 8; ++w2) s += regA[w2][0][i2];
    out[((size_t)(b * LQ_N + qbase) << 6) + i2] = s;
  }
}

extern "C" void kernel_launch(void* const* d_in, const int* in_sizes, int n_in,
                              void* d_out, int out_size, void* d_ws, size_t ws_size,
                              hipStream_t stream) {
  const float* q   = (const float*)d_in[0];
  const float* k   = (const float*)d_in[1];
  const float* v   = (const float*)d_in[2];
  const float* td  = (const float*)d_in[3];
  const unsigned char* mask = (const unsigned char*)d_in[4];
  const float* tpw = (const float*)d_in[5];
  const float* tmw = (const float*)d_in[6];
  float* out  = (float*)d_out;
  float* attn = out + (size_t)B_N * LQ_N * D_N;
  float* wsf  = (float*)d_ws;

  red1_kernel<<<2048, 256, 0, stream>>>(td, wsf);
  red2_kernel<<<1, 256, 0, stream>>>(tpw, (const unsigned*)mask, wsf);
  attn_kernel<<<2048, 512, 0, stream>>>(q, k, v, td, mask, tmw, wsf, out, attn);
}

// Round 7
// 502.784 us; speedup vs baseline: 1.0387x; 1.0387x over previous
//
#include <hip/hip_runtime.h>
#include <hip/hip_bf16.h>

#define B_N 16
#define LQ_N 2048
#define LK_N 2048
#define D_N 64

typedef __attribute__((ext_vector_type(8))) __bf16 bf16x8;
typedef __attribute__((ext_vector_type(4))) float f32x4;
typedef __attribute__((ext_vector_type(2))) unsigned u32x2;
typedef __attribute__((ext_vector_type(4))) unsigned u32x4;

__device__ __forceinline__ unsigned cvt_pk_bf16(float lo, float hi) {
  unsigned r;
  asm("v_cvt_pk_bf16_f32 %0, %1, %2" : "=v"(r) : "v"(lo), "v"(hi));
  return r;
}

__device__ __forceinline__ void gl_lds16(const float* g, float* l) {
  __builtin_amdgcn_global_load_lds(
      (const __attribute__((address_space(1))) void*)g,
      (__attribute__((address_space(3))) void*)l, 16, 0, 0);
}

#define WAIT_VMC(N)  do { asm volatile("s_waitcnt vmcnt(" #N ")" ::: "memory"); __builtin_amdgcn_sched_barrier(0); } while (0)
#define WAIT_LGKM0() do { asm volatile("s_waitcnt lgkmcnt(0)" ::: "memory");    __builtin_amdgcn_sched_barrier(0); } while (0)
#define SBAR()       __builtin_amdgcn_sched_barrier(0)

// ---------- pass 1: global sum & max of time_diff ----------
__global__ __launch_bounds__(256) void red1_kernel(const float* __restrict__ td,
                                                   float* __restrict__ ws) {
  const int tid = threadIdx.x;
  const int gid = blockIdx.x * 256 + tid;
  float s = 0.f, mx = -1e30f;
  const float4* p = reinterpret_cast<const float4*>(td);
  for (int i = gid; i < 16777216; i += 524288) {
    float4 x = p[i];
    s += (x.x + x.y) + (x.z + x.w);
    mx = fmaxf(mx, fmaxf(fmaxf(x.x, x.y), fmaxf(x.z, x.w)));
  }
#pragma unroll
  for (int m = 1; m < 64; m <<= 1) {
    s += __shfl_xor(s, m, 64);
    mx = fmaxf(mx, __shfl_xor(mx, m, 64));
  }
  __shared__ float ss[4], sm[4];
  if ((tid & 63) == 0) { ss[tid >> 6] = s; sm[tid >> 6] = mx; }
  __syncthreads();
  if (tid == 0) {
    ws[blockIdx.x]        = (ss[0] + ss[1]) + (ss[2] + ss[3]);
    ws[2048 + blockIdx.x] = fmaxf(fmaxf(sm[0], sm[1]), fmaxf(sm[2], sm[3]));
  }
}

// final reduce + scalar prep + mask-layout detection (byte vs int32 bool)
__global__ __launch_bounds__(256) void red2_kernel(const float* __restrict__ tpw,
                                                   const unsigned* __restrict__ mku,
                                                   float* __restrict__ ws) {
  const int tid = threadIdx.x;
  double s = 0.0; float mx = -1e30f;
  for (int i = tid; i < 2048; i += 256) { s += (double)ws[i]; mx = fmaxf(mx, ws[2048 + i]); }
#pragma unroll
  for (int m = 1; m < 64; m <<= 1) {
    s += __shfl_xor(s, m, 64);
    mx = fmaxf(mx, __shfl_xor(mx, m, 64));
  }
  unsigned big = 0;
  for (int i = tid; i < 1024; i += 256) big |= (mku[i] > 1u) ? 1u : 0u;
  const int anyw = __any(big != 0);
  __shared__ double sd[4]; __shared__ float sm[4]; __shared__ int sa[4];
  if ((tid & 63) == 0) { sd[tid >> 6] = s; sm[tid >> 6] = mx; sa[tid >> 6] = anyw; }
  __syncthreads();
  if (tid == 0) {
    double tot = (sd[0] + sd[1]) + (sd[2] + sd[3]);
    float m4 = fmaxf(fmaxf(sm[0], sm[1]), fmaxf(sm[2], sm[3]));
    double mean = tot / 67108864.0;
    float inv_mean = (float)(1.0 / mean);
    float sp = log1pf(__expf(tpw[0]));
    ws[4096] = inv_mean;
    ws[4097] = sp * m4 * inv_mean;                      // bias_c
    ws[4098] = (sa[0] | sa[1] | sa[2] | sa[3]) ? 1.f : 0.f;  // 1 = byte mask, 0 = int32
    ws[4099] = 2.718281828459045f + sp * m4 * inv_mean; // ec = e + bias_c
  }
}

// ---------- pass 2: fused QK^T + bias + mask + softmax + attn-write + PV ----------
// 512 thr (8 waves), 16 q-rows/block. SWAPPED QK^T (mfma(K,Q) -> S^T tile): each lane
// holds q-row=lrow, 4 consecutive j -> td/mask/attn are float4/u32/dwordx4 per chunk.
// Wave-private K/V chunks, global_load_lds double-buffered depth-2; td/mask 3-deep
// register prefetch; exp2-domain softmax; counted vmcnt (never 0 mid-loop).
// waves_per_eu(4,4): LDS caps at 2 blocks/CU (= 4 waves/EU), so pin the allocator's
// occupancy target there -> 128-VGPR budget, no spill-to-reach-tier-8 (r4-r6 bug).
__global__ __launch_bounds__(512) __attribute__((amdgpu_waves_per_eu(4, 4)))
void attn_kernel(
    const float* __restrict__ q, const float* __restrict__ kp, const float* __restrict__ vp,
    const float* __restrict__ td, const unsigned char* __restrict__ maskb,
    const float* __restrict__ tmwp, const float* __restrict__ ws,
    float* __restrict__ out, float* __restrict__ attn) {

  __shared__ float regA[8][2][1024];         // 64 KB: per-wave double-buffered K/V chunk
  __shared__ float Qs[16 * 68];
  __shared__ unsigned short Ps[8][16 * 24];  // per-wave P bridge; 48B row stride (16B-mult)
  __shared__ float rsum[8][16];

  const int tid  = threadIdx.x;
  const int w    = tid >> 6;
  const int lane = tid & 63;
  const int lrow = lane & 15;
  const int lgrp = lane >> 4;

  const int b     = blockIdx.x >> 7;
  const int qbase = (blockIdx.x & 127) << 4;

  const float inv_mean = ws[4096];
  const float ec       = ws[4099];                       // e + bias_c
  const float tmw      = tmwp[0];
  const float sc       = tmw * 2.0813689810056077f;      // tmw * log2e / ln2
  const int   msh      = (ws[4098] != 0.f) ? 0 : 2;

  // ---- stage Q f32, pre-scaled by log2e/temperature ----
  {
    const float qscale = 0.18033688011112042f;           // 0.125 * log2e
    const int g = tid * 2, row = g >> 6, col = g & 63;
    const float* qp0 = q + ((size_t)(b * LQ_N + qbase + row) << 6) + col;
    Qs[row * 68 + col]     = qp0[0] * qscale;
    Qs[row * 68 + col + 1] = qp0[1] * qscale;
  }
  __syncthreads();

  bf16x8 qa[2];
#pragma unroll
  for (int h = 0; h < 2; ++h) {
    f32x4 a0 = *(const f32x4*)&Qs[lrow * 68 + h * 32 + lgrp * 8];
    f32x4 a1 = *(const f32x4*)&Qs[lrow * 68 + h * 32 + lgrp * 8 + 4];
    u32x4 kd = { cvt_pk_bf16(a0[0], a0[1]), cvt_pk_bf16(a0[2], a0[3]),
                 cvt_pk_bf16(a1[0], a1[1]), cvt_pk_bf16(a1[2], a1[3]) };
    qa[h] = __builtin_bit_cast(bf16x8, kd);
  }

  // 32-bit element offsets. Post-swap elementwise layout: q-row = lrow, j-base = lgrp*4.
  const unsigned qrow = (unsigned)(b * LQ_N + qbase + lrow);
  const unsigned tdo0 = (qrow << 11) + (unsigned)(w * 16 + lgrp * 4);
  const unsigned kvo0 = ((unsigned)b << 17) + ((unsigned)w << 10);
  const unsigned pA = (lgrp << 6) + ((lrow ^ lgrp)       << 2);
  const unsigned pB = (lgrp << 6) + ((lrow ^ (lgrp + 4)) << 2);

  // wave-private DMA: 16 rows x 64 f32; LDS dest linear, source slot-permuted
  auto dma16 = [&](const float* src_base, int c, int pb) {
    const unsigned base = kvo0 + (unsigned)c * 8192u;
    gl_lds16(src_base + (base         + pA), &regA[w][pb][0]);
    gl_lds16(src_base + (base +  256u + pB), &regA[w][pb][256]);
    gl_lds16(src_base + (base +  512u + pA), &regA[w][pb][512]);
    gl_lds16(src_base + (base +  768u + pB), &regA[w][pb][768]);
  };

  // td float4 (NT) + mask 4-wide, one load each
  auto ldtd = [&](int c, f32x4* tdv, unsigned* mk4) {
    const unsigned to = tdo0 + (unsigned)c * 128u;
    *tdv = __builtin_nontemporal_load(reinterpret_cast<const f32x4*>(td + to));
    if (msh == 0) {
      *mk4 = *reinterpret_cast<const unsigned*>(maskb + to);
    } else {
      u32x4 m = __builtin_nontemporal_load(
          reinterpret_cast<const u32x4*>(maskb + ((size_t)to << 2)));
      *mk4 = (m[0] & 1u) | ((m[1] & 1u) << 8) | ((m[2] & 1u) << 16) | ((m[3] & 1u) << 24);
    }
  };

  // ---- phase 1: QK^T(swapped) + bias + mask + exp2 ----
  dma16(kp, 0, 0); SBAR();
  dma16(kp, 1, 1); SBAR();
  f32x4    tdb[3];
  unsigned mkb[3];
  ldtd(0, &tdb[0], &mkb[0]); SBAR();
  ldtd(1, &tdb[1], &mkb[1]); SBAR();

  float rs = 0.f;
  u32x2 E[16];

#pragma unroll
  for (int c = 0; c < 16; ++c) {
    // top: ensure dma(c) done. issue order: D0 D1 L0 L1 | iter c: L(c+2), D(c+2)
    if (c == 0)       { WAIT_VMC(8);  }
    else if (c == 1)  { WAIT_VMC(10); }
    else if (c == 15) { WAIT_VMC(0);  }
    else              { WAIT_VMC(6);  }

    if (c < 14) { ldtd(c + 2, &tdb[(c + 2) % 3], &mkb[(c + 2) % 3]); SBAR(); }

    f32x4 acc = {0.f, 0.f, 0.f, 0.f};
#pragma unroll
    for (int h = 0; h < 2; ++h) {
      const int g0 = (h * 8 + lgrp * 2 + 0) ^ (lrow & 7);
      const int g1 = (h * 8 + lgrp * 2 + 1) ^ (lrow & 7);
      f32x4 ka = *(const f32x4*)&regA[w][c & 1][lrow * 64 + g0 * 4];
      f32x4 kc = *(const f32x4*)&regA[w][c & 1][lrow * 64 + g1 * 4];
      u32x4 kd = { cvt_pk_bf16(ka[0], ka[1]), cvt_pk_bf16(ka[2], ka[3]),
                   cvt_pk_bf16(kc[0], kc[1]), cvt_pk_bf16(kc[2], kc[3]) };
      // SWAPPED: A=K, B=Q -> D[j][q]; lane holds q=lrow, j = base + lgrp*4 + i
      acc = __builtin_amdgcn_mfma_f32_16x16x32_bf16(__builtin_bit_cast(bf16x8, kd), qa[h],
                                                    acc, 0, 0, 0);
    }
    WAIT_LGKM0();                              // buffer (c&1) reusable
    if (c < 14) { dma16(kp, c + 2, c & 1); SBAR(); }

    // mid: ensure ldtd(c) done
    if (c == 0)       { WAIT_VMC(8);  }
    else if (c == 1)  { WAIT_VMC(12); }
    else if (c == 14) { WAIT_VMC(10); }
    else if (c == 15) { WAIT_VMC(0);  }
    else              { WAIT_VMC(16); }

    const f32x4    tv  = tdb[c % 3];
    const unsigned mk4 = mkb[c % 3];
    float e4[4];
#pragma unroll
    for (int i = 0; i < 4; ++i) {
      const float z  = __builtin_fmaf(tv[i], inv_mean, ec);
      const float l2 = __builtin_amdgcn_logf(z);          // log2(z)
      const float r  = __builtin_amdgcn_rcpf(l2);
      const float sv = __builtin_fmaf(sc, r, acc[i]);
      const float e  = ((mk4 >> (8 * i)) & 0xffu) ? 0.f : __builtin_amdgcn_exp2f(sv);
      e4[i] = e;
      rs += e;
    }
    E[c] = u32x2{ cvt_pk_bf16(e4[0], e4[1]), cvt_pk_bf16(e4[2], e4[3]) };
  }

  // ---- V DMA prologue: latency hides under the rsum reduction ----
  dma16(vp, 0, 0); SBAR();
  dma16(vp, 1, 1); SBAR();

  // ---- row sum (q-row = lrow): reduce over lgrp, then cross-wave ----
  rs += __shfl_xor(rs, 16, 64);
  rs += __shfl_xor(rs, 32, 64);
  if (lgrp == 0) rsum[w][lrow] = rs;
  __syncthreads();
  float invl;
  {
    float s = 0.f;
#pragma unroll
    for (int w2 = 0; w2 < 8; ++w2) s += rsum[w2][lrow];
    invl = __fdividef(1.f, s);
  }

  // ---- phase 2: attn write + PV ----
  f32x4 oacc[4];
#pragma unroll
  for (int n = 0; n < 4; ++n) oacc[n] = {0.f, 0.f, 0.f, 0.f};

  const u32x4 zz = {0u, 0u, 0u, 0u};
#pragma unroll
  for (int c = 0; c < 16; ++c) {
    // top: ensure dma(c) done. issue order: D0 D1 | iter c: D(c+2), S(c)  (S = 1 store)
    if (c == 0)       { WAIT_VMC(4); }
    else if (c == 1)  { WAIT_VMC(5); }
    else if (c == 15) { WAIT_VMC(2); }
    else              { WAIT_VMC(6); }

    const unsigned ex = E[c][0], ey = E[c][1];
    f32x4 pv;
    pv[0] = __uint_as_float(ex << 16)         * invl;
    pv[1] = __uint_as_float(ex & 0xffff0000u) * invl;
    pv[2] = __uint_as_float(ey << 16)         * invl;
    pv[3] = __uint_as_float(ey & 0xffff0000u) * invl;

    // P bridge: row = lrow (q), cols lgrp*4..+3 -> one b64 write (48B row stride)
    const unsigned d01 = cvt_pk_bf16(pv[0], pv[1]);
    const unsigned d23 = cvt_pk_bf16(pv[2], pv[3]);
    *reinterpret_cast<u32x2*>(&Ps[w][lrow * 24 + lgrp * 4]) = u32x2{ d01, d23 };

    bf16x8 pa;
    if (lgrp < 2) pa = *(const bf16x8*)&Ps[w][lrow * 24 + lgrp * 8];
    else          pa = __builtin_bit_cast(bf16x8, zz);

#pragma unroll
    for (int n = 0; n < 4; ++n) {
      u32x4 vd;
      if (lgrp < 2) {
        float vv[8];
#pragma unroll
        for (int e = 0; e < 8; ++e) {
          const int r    = lgrp * 8 + e;
          const int dcol = n * 16 + lrow;
          const int slot = (dcol >> 2) ^ (r & 7);
          vv[e] = regA[w][c & 1][r * 64 + slot * 4 + (dcol & 3)];
        }
        vd = u32x4{ cvt_pk_bf16(vv[0], vv[1]), cvt_pk_bf16(vv[2], vv[3]),
                    cvt_pk_bf16(vv[4], vv[5]), cvt_pk_bf16(vv[6], vv[7]) };
      } else {
        vd = zz;
      }
      oacc[n] = __builtin_amdgcn_mfma_f32_16x16x32_bf16(pa, __builtin_bit_cast(bf16x8, vd),
                                                        oacc[n], 0, 0, 0);
    }

    WAIT_LGKM0();                              // all regA[c&1] reads done
    if (c < 14) { dma16(vp, c + 2, c & 1); SBAR(); }

    __builtin_nontemporal_store(pv, reinterpret_cast<f32x4*>(attn + tdo0 + (unsigned)c * 128u));
  }

  // ---- cross-wave O reduction ----
#pragma unroll
  for (int n = 0; n < 4; ++n)
#pragma unroll
    for (int i = 0; i < 4; ++i)
      regA[w][0][(lgrp * 4 + i) * 64 + n * 16 + lrow] = oacc[n][i];
  __syncthreads();
  for (int i2 = tid; i2 < 1024; i2 += 512) {
    float s = 0.f;
#pragma unroll
    for (int w2 = 0; w2 < 8; ++w2) s += regA[w2][0][i2];
    out[((size_t)(b * LQ_N + qbase) << 6) + i2] = s;
  }
}

extern "C" void kernel_launch(void* const* d_in, const int* in_sizes, int n_in,
                              void* d_out, int out_size, void* d_ws, size_t ws_size,
                              hipStream_t stream) {
  const float* q   = (const float*)d_in[0];
  const float* k   = (const float*)d_in[1];
  const float* v   = (const float*)d_in[2];
  const float* td  = (const float*)d_in[3];
  const unsigned char* mask = (const unsigned char*)d_in[4];
  const float* tpw = (const float*)d_in[5];
  const float* tmw = (const float*)d_in[6];
  float* out  = (float*)d_out;
  float* attn = out + (size_t)B_N * LQ_N * D_N;
  float* wsf  = (float*)d_ws;

  red1_kernel<<<2048, 256, 0, stream>>>(td, wsf);
  red2_kernel<<<1, 256, 0, stream>>>(tpw, (const unsigned*)mask, wsf);
  attn_kernel<<<2048, 512, 0, stream>>>(q, k, v, td, mask, tmw, wsf, out, attn);
}

// Round 8
// 313.276 us; speedup vs baseline: 1.6670x; 1.6049x over previous
//
#include <hip/hip_runtime.h>
#include <hip/hip_bf16.h>

#define B_N 16
#define LQ_N 2048
#define LK_N 2048
#define D_N 64

typedef __attribute__((ext_vector_type(8))) __bf16 bf16x8;
typedef __attribute__((ext_vector_type(4))) float f32x4;
typedef __attribute__((ext_vector_type(2))) unsigned u32x2;
typedef __attribute__((ext_vector_type(4))) unsigned u32x4;

__device__ __forceinline__ unsigned cvt_pk_bf16(float lo, float hi) {
  unsigned r;
  asm("v_cvt_pk_bf16_f32 %0, %1, %2" : "=v"(r) : "v"(lo), "v"(hi));
  return r;
}

__device__ __forceinline__ void gl_lds16(const float* g, float* l) {
  __builtin_amdgcn_global_load_lds(
      (const __attribute__((address_space(1))) void*)g,
      (__attribute__((address_space(3))) void*)l, 16, 0, 0);
}

#define WAIT_VMC(N)  do { asm volatile("s_waitcnt vmcnt(" #N ")" ::: "memory"); __builtin_amdgcn_sched_barrier(0); } while (0)
#define WAIT_LGKM0() do { asm volatile("s_waitcnt lgkmcnt(0)" ::: "memory");    __builtin_amdgcn_sched_barrier(0); } while (0)
#define SBAR()       __builtin_amdgcn_sched_barrier(0)

// ---------- pass 1: global sum & max of time_diff ----------
__global__ __launch_bounds__(256) void red1_kernel(const float* __restrict__ td,
                                                   float* __restrict__ ws) {
  const int tid = threadIdx.x;
  const int gid = blockIdx.x * 256 + tid;
  float s = 0.f, mx = -1e30f;
  const float4* p = reinterpret_cast<const float4*>(td);
  for (int i = gid; i < 16777216; i += 524288) {
    float4 x = p[i];
    s += (x.x + x.y) + (x.z + x.w);
    mx = fmaxf(mx, fmaxf(fmaxf(x.x, x.y), fmaxf(x.z, x.w)));
  }
#pragma unroll
  for (int m = 1; m < 64; m <<= 1) {
    s += __shfl_xor(s, m, 64);
    mx = fmaxf(mx, __shfl_xor(mx, m, 64));
  }
  __shared__ float ss[4], sm[4];
  if ((tid & 63) == 0) { ss[tid >> 6] = s; sm[tid >> 6] = mx; }
  __syncthreads();
  if (tid == 0) {
    ws[blockIdx.x]        = (ss[0] + ss[1]) + (ss[2] + ss[3]);
    ws[2048 + blockIdx.x] = fmaxf(fmaxf(sm[0], sm[1]), fmaxf(sm[2], sm[3]));
  }
}

// final reduce + scalar prep + mask-layout detection (byte vs int32 bool)
__global__ __launch_bounds__(256) void red2_kernel(const float* __restrict__ tpw,
                                                   const unsigned* __restrict__ mku,
                                                   float* __restrict__ ws) {
  const int tid = threadIdx.x;
  double s = 0.0; float mx = -1e30f;
  for (int i = tid; i < 2048; i += 256) { s += (double)ws[i]; mx = fmaxf(mx, ws[2048 + i]); }
#pragma unroll
  for (int m = 1; m < 64; m <<= 1) {
    s += __shfl_xor(s, m, 64);
    mx = fmaxf(mx, __shfl_xor(mx, m, 64));
  }
  unsigned big = 0;
  for (int i = tid; i < 1024; i += 256) big |= (mku[i] > 1u) ? 1u : 0u;
  const int anyw = __any(big != 0);
  __shared__ double sd[4]; __shared__ float sm[4]; __shared__ int sa[4];
  if ((tid & 63) == 0) { sd[tid >> 6] = s; sm[tid >> 6] = mx; sa[tid >> 6] = anyw; }
  __syncthreads();
  if (tid == 0) {
    double tot = (sd[0] + sd[1]) + (sd[2] + sd[3]);
    float m4 = fmaxf(fmaxf(sm[0], sm[1]), fmaxf(sm[2], sm[3]));
    double mean = tot / 67108864.0;
    float inv_mean = (float)(1.0 / mean);
    float sp = log1pf(__expf(tpw[0]));
    ws[4096] = inv_mean;
    ws[4097] = sp * m4 * inv_mean;                      // bias_c
    ws[4098] = (sa[0] | sa[1] | sa[2] | sa[3]) ? 1.f : 0.f;  // 1 = byte mask, 0 = int32
    ws[4099] = 2.718281828459045f + sp * m4 * inv_mean; // ec = e + bias_c
  }
}

// ---------- pass 2: fused QK^T + bias + mask + softmax + attn-write + PV ----------
// 512 thr (8 waves), 16 q-rows/block. SWAPPED QK^T (mfma(K,Q) -> S^T tile): each lane
// holds q-row=lrow, 4 consecutive j -> td/mask/attn are float4/u32/dwordx4 per chunk.
// Wave-private K/V chunks, global_load_lds double-buffered depth-2; td/mask 3-deep
// register prefetch; exp2-domain softmax; counted vmcnt (never 0 mid-loop).
// PLAIN __launch_bounds__(512): any occupancy hint ((512,4)/(512,6)/waves_per_eu(4,4))
// makes the allocator split the unified file at 64 arch VGPRs -> chronic scratch spill
// (r3-r7: +300/+500 MB FETCH/WRITE). r2 proved plain bounds -> 128 regs, zero spill.
__global__ __launch_bounds__(512)
void attn_kernel(
    const float* __restrict__ q, const float* __restrict__ kp, const float* __restrict__ vp,
    const float* __restrict__ td, const unsigned char* __restrict__ maskb,
    const float* __restrict__ tmwp, const float* __restrict__ ws,
    float* __restrict__ out, float* __restrict__ attn) {

  __shared__ float regA[8][2][1024];         // 64 KB: per-wave double-buffered K/V chunk
  __shared__ float Qs[16 * 68];
  __shared__ unsigned short Ps[8][16 * 24];  // per-wave P bridge; 48B row stride (16B-mult)
  __shared__ float rsum[8][16];

  const int tid  = threadIdx.x;
  const int w    = tid >> 6;
  const int lane = tid & 63;
  const int lrow = lane & 15;
  const int lgrp = lane >> 4;

  const int b     = blockIdx.x >> 7;
  const int qbase = (blockIdx.x & 127) << 4;

  const float inv_mean = ws[4096];
  const float ec       = ws[4099];                       // e + bias_c
  const float tmw      = tmwp[0];
  const float sc       = tmw * 2.0813689810056077f;      // tmw * log2e / ln2
  const int   msh      = (ws[4098] != 0.f) ? 0 : 2;

  // ---- stage Q f32, pre-scaled by log2e/temperature ----
  {
    const float qscale = 0.18033688011112042f;           // 0.125 * log2e
    const int g = tid * 2, row = g >> 6, col = g & 63;
    const float* qp0 = q + ((size_t)(b * LQ_N + qbase + row) << 6) + col;
    Qs[row * 68 + col]     = qp0[0] * qscale;
    Qs[row * 68 + col + 1] = qp0[1] * qscale;
  }
  __syncthreads();

  bf16x8 qa[2];
#pragma unroll
  for (int h = 0; h < 2; ++h) {
    f32x4 a0 = *(const f32x4*)&Qs[lrow * 68 + h * 32 + lgrp * 8];
    f32x4 a1 = *(const f32x4*)&Qs[lrow * 68 + h * 32 + lgrp * 8 + 4];
    u32x4 kd = { cvt_pk_bf16(a0[0], a0[1]), cvt_pk_bf16(a0[2], a0[3]),
                 cvt_pk_bf16(a1[0], a1[1]), cvt_pk_bf16(a1[2], a1[3]) };
    qa[h] = __builtin_bit_cast(bf16x8, kd);
  }

  // 32-bit element offsets. Post-swap elementwise layout: q-row = lrow, j-base = lgrp*4.
  const unsigned qrow = (unsigned)(b * LQ_N + qbase + lrow);
  const unsigned tdo0 = (qrow << 11) + (unsigned)(w * 16 + lgrp * 4);
  const unsigned kvo0 = ((unsigned)b << 17) + ((unsigned)w << 10);
  const unsigned pA = (lgrp << 6) + ((lrow ^ lgrp)       << 2);
  const unsigned pB = (lgrp << 6) + ((lrow ^ (lgrp + 4)) << 2);

  // wave-private DMA: 16 rows x 64 f32; LDS dest linear, source slot-permuted
  auto dma16 = [&](const float* src_base, int c, int pb) {
    const unsigned base = kvo0 + (unsigned)c * 8192u;
    gl_lds16(src_base + (base         + pA), &regA[w][pb][0]);
    gl_lds16(src_base + (base +  256u + pB), &regA[w][pb][256]);
    gl_lds16(src_base + (base +  512u + pA), &regA[w][pb][512]);
    gl_lds16(src_base + (base +  768u + pB), &regA[w][pb][768]);
  };

  // td float4 (NT) + mask 4-wide, one load each
  auto ldtd = [&](int c, f32x4* tdv, unsigned* mk4) {
    const unsigned to = tdo0 + (unsigned)c * 128u;
    *tdv = __builtin_nontemporal_load(reinterpret_cast<const f32x4*>(td + to));
    if (msh == 0) {
      *mk4 = *reinterpret_cast<const unsigned*>(maskb + to);
    } else {
      u32x4 m = __builtin_nontemporal_load(
          reinterpret_cast<const u32x4*>(maskb + ((size_t)to << 2)));
      *mk4 = (m[0] & 1u) | ((m[1] & 1u) << 8) | ((m[2] & 1u) << 16) | ((m[3] & 1u) << 24);
    }
  };

  // ---- phase 1: QK^T(swapped) + bias + mask + exp2 ----
  dma16(kp, 0, 0); SBAR();
  dma16(kp, 1, 1); SBAR();
  f32x4    tdb[3];
  unsigned mkb[3];
  ldtd(0, &tdb[0], &mkb[0]); SBAR();
  ldtd(1, &tdb[1], &mkb[1]); SBAR();

  float rs = 0.f;
  u32x2 E[16];

#pragma unroll
  for (int c = 0; c < 16; ++c) {
    // top: ensure dma(c) done. issue order: D0 D1 L0 L1 | iter c: L(c+2), D(c+2)
    if (c == 0)       { WAIT_VMC(8);  }
    else if (c == 1)  { WAIT_VMC(10); }
    else if (c == 15) { WAIT_VMC(0);  }
    else              { WAIT_VMC(6);  }

    if (c < 14) { ldtd(c + 2, &tdb[(c + 2) % 3], &mkb[(c + 2) % 3]); SBAR(); }

    f32x4 acc = {0.f, 0.f, 0.f, 0.f};
#pragma unroll
    for (int h = 0; h < 2; ++h) {
      const int g0 = (h * 8 + lgrp * 2 + 0) ^ (lrow & 7);
      const int g1 = (h * 8 + lgrp * 2 + 1) ^ (lrow & 7);
      f32x4 ka = *(const f32x4*)&regA[w][c & 1][lrow * 64 + g0 * 4];
      f32x4 kc = *(const f32x4*)&regA[w][c & 1][lrow * 64 + g1 * 4];
      u32x4 kd = { cvt_pk_bf16(ka[0], ka[1]), cvt_pk_bf16(ka[2], ka[3]),
                   cvt_pk_bf16(kc[0], kc[1]), cvt_pk_bf16(kc[2], kc[3]) };
      // SWAPPED: A=K, B=Q -> D[j][q]; lane holds q=lrow, j = base + lgrp*4 + i
      acc = __builtin_amdgcn_mfma_f32_16x16x32_bf16(__builtin_bit_cast(bf16x8, kd), qa[h],
                                                    acc, 0, 0, 0);
    }
    WAIT_LGKM0();                              // buffer (c&1) reusable
    if (c < 14) { dma16(kp, c + 2, c & 1); SBAR(); }

    // mid: ensure ldtd(c) done
    if (c == 0)       { WAIT_VMC(8);  }
    else if (c == 1)  { WAIT_VMC(12); }
    else if (c == 14) { WAIT_VMC(10); }
    else if (c == 15) { WAIT_VMC(0);  }
    else              { WAIT_VMC(16); }

    const f32x4    tv  = tdb[c % 3];
    const unsigned mk4 = mkb[c % 3];
    float e4[4];
#pragma unroll
    for (int i = 0; i < 4; ++i) {
      const float z  = __builtin_fmaf(tv[i], inv_mean, ec);
      const float l2 = __builtin_amdgcn_logf(z);          // log2(z)
      const float r  = __builtin_amdgcn_rcpf(l2);
      const float sv = __builtin_fmaf(sc, r, acc[i]);
      const float e  = ((mk4 >> (8 * i)) & 0xffu) ? 0.f : __builtin_amdgcn_exp2f(sv);
      e4[i] = e;
      rs += e;
    }
    E[c] = u32x2{ cvt_pk_bf16(e4[0], e4[1]), cvt_pk_bf16(e4[2], e4[3]) };
  }

  // ---- V DMA prologue: latency hides under the rsum reduction ----
  dma16(vp, 0, 0); SBAR();
  dma16(vp, 1, 1); SBAR();

  // ---- row sum (q-row = lrow): reduce over lgrp, then cross-wave ----
  rs += __shfl_xor(rs, 16, 64);
  rs += __shfl_xor(rs, 32, 64);
  if (lgrp == 0) rsum[w][lrow] = rs;
  __syncthreads();
  float invl;
  {
    float s = 0.f;
#pragma unroll
    for (int w2 = 0; w2 < 8; ++w2) s += rsum[w2][lrow];
    invl = __fdividef(1.f, s);
  }

  // ---- phase 2: attn write + PV ----
  f32x4 oacc[4];
#pragma unroll
  for (int n = 0; n < 4; ++n) oacc[n] = {0.f, 0.f, 0.f, 0.f};

  const u32x4 zz = {0u, 0u, 0u, 0u};
#pragma unroll
  for (int c = 0; c < 16; ++c) {
    // top: ensure dma(c) done. issue order: D0 D1 | iter c: D(c+2), S(c)  (S = 1 store)
    if (c == 0)       { WAIT_VMC(4); }
    else if (c == 1)  { WAIT_VMC(5); }
    else if (c == 15) { WAIT_VMC(2); }
    else              { WAIT_VMC(6); }

    const unsigned ex = E[c][0], ey = E[c][1];
    f32x4 pv;
    pv[0] = __uint_as_float(ex << 16)         * invl;
    pv[1] = __uint_as_float(ex & 0xffff0000u) * invl;
    pv[2] = __uint_as_float(ey << 16)         * invl;
    pv[3] = __uint_as_float(ey & 0xffff0000u) * invl;

    // P bridge: row = lrow (q), cols lgrp*4..+3 -> one b64 write (48B row stride)
    const unsigned d01 = cvt_pk_bf16(pv[0], pv[1]);
    const unsigned d23 = cvt_pk_bf16(pv[2], pv[3]);
    *reinterpret_cast<u32x2*>(&Ps[w][lrow * 24 + lgrp * 4]) = u32x2{ d01, d23 };

    bf16x8 pa;
    if (lgrp < 2) pa = *(const bf16x8*)&Ps[w][lrow * 24 + lgrp * 8];
    else          pa = __builtin_bit_cast(bf16x8, zz);

#pragma unroll
    for (int n = 0; n < 4; ++n) {
      u32x4 vd;
      if (lgrp < 2) {
        float vv[8];
#pragma unroll
        for (int e = 0; e < 8; ++e) {
          const int r    = lgrp * 8 + e;
          const int dcol = n * 16 + lrow;
          const int slot = (dcol >> 2) ^ (r & 7);
          vv[e] = regA[w][c & 1][r * 64 + slot * 4 + (dcol & 3)];
        }
        vd = u32x4{ cvt_pk_bf16(vv[0], vv[1]), cvt_pk_bf16(vv[2], vv[3]),
                    cvt_pk_bf16(vv[4], vv[5]), cvt_pk_bf16(vv[6], vv[7]) };
      } else {
        vd = zz;
      }
      oacc[n] = __builtin_amdgcn_mfma_f32_16x16x32_bf16(pa, __builtin_bit_cast(bf16x8, vd),
                                                        oacc[n], 0, 0, 0);
    }

    WAIT_LGKM0();                              // all regA[c&1] reads done
    if (c < 14) { dma16(vp, c + 2, c & 1); SBAR(); }

    __builtin_nontemporal_store(pv, reinterpret_cast<f32x4*>(attn + tdo0 + (unsigned)c * 128u));
  }

  // ---- cross-wave O reduction ----
#pragma unroll
  for (int n = 0; n < 4; ++n)
#pragma unroll
    for (int i = 0; i < 4; ++i)
      regA[w][0][(lgrp * 4 + i) * 64 + n * 16 + lrow] = oacc[n][i];
  __syncthreads();
  for (int i2 = tid; i2 < 1024; i2 += 512) {
    float s = 0.f;
#pragma unroll
    for (int w2 = 0; w2 < 8; ++w2) s += regA[w2][0][i2];
    out[((size_t)(b * LQ_N + qbase) << 6) + i2] = s;
  }
}

extern "C" void kernel_launch(void* const* d_in, const int* in_sizes, int n_in,
                              void* d_out, int out_size, void* d_ws, size_t ws_size,
                              hipStream_t stream) {
  const float* q   = (const float*)d_in[0];
  const float* k   = (const float*)d_in[1];
  const float* v   = (const float*)d_in[2];
  const float* td  = (const float*)d_in[3];
  const unsigned char* mask = (const unsigned char*)d_in[4];
  const float* tpw = (const float*)d_in[5];
  const float* tmw = (const float*)d_in[6];
  float* out  = (float*)d_out;
  float* attn = out + (size_t)B_N * LQ_N * D_N;
  float* wsf  = (float*)d_ws;

  red1_kernel<<<2048, 256, 0, stream>>>(td, wsf);
  red2_kernel<<<1, 256, 0, stream>>>(tpw, (const unsigned*)mask, wsf);
  attn_kernel<<<2048, 512, 0, stream>>>(q, k, v, td, mask, tmw, wsf, out, attn);
}